// Round 4
// baseline (389.158 us; speedup 1.0000x reference)
//
#include <hip/hip_runtime.h>

typedef unsigned short u16;
typedef __bf16 bf16x8 __attribute__((ext_vector_type(8)));
typedef float f32x4 __attribute__((ext_vector_type(4)));
typedef u16 u16x8 __attribute__((ext_vector_type(8)));

#define B_    8
#define CIN   512
#define COUT  512
#define KT    5
#define LEN   4096
#define RED_  128
#define KDIM  (KT * CIN)   /* 2560 */
#define LP    (LEN + 4)    /* 4100: pad 2 each side along L */

#define XT_B  ((size_t)LP * CIN)     /* elems per batch in xT  (2,099,200) */
#define WB_B  ((size_t)COUT * KDIM)  /* elems per batch in wb  (1,310,720) */

__device__ __forceinline__ float bf2f(u16 u) {
    return __uint_as_float(((unsigned int)u) << 16);
}
__device__ __forceinline__ u16 f2bf(float f) {
    unsigned int u = __float_as_uint(f);
    u += 0x7fffu + ((u >> 16) & 1u);   // RNE
    return (u16)(u >> 16);
}
// dtype-agnostic scalar input read: isf=1 -> fp32 buffer, isf=0 -> bf16 buffer
__device__ __forceinline__ float getv(const void* p, size_t i, int isf) {
    return isf ? ((const float*)p)[i] : bf2f(((const u16*)p)[i]);
}

// ------------- dtype detector: fp32 low half-words have wild exponents -------------
__global__ void detect_kernel(const void* __restrict__ xv, int* __restrict__ flag) {
    const u16* p = (const u16*)xv;
    int c = 0;
    for (int i = threadIdx.x; i < 4096; i += 256) {
        int e = (p[i] >> 7) & 0xFF;          // bf16 exponent field
        c += (e >= 0x90) ? 1 : 0;            // impossible for N(0,1) bf16 data
    }
#pragma unroll
    for (int off = 32; off > 0; off >>= 1) c += __shfl_down(c, off, 64);
    __shared__ int red[4];
    if ((threadIdx.x & 63) == 0) red[threadIdx.x >> 6] = c;
    __syncthreads();
    if (threadIdx.x == 0)
        flag[0] = (red[0] + red[1] + red[2] + red[3] > 256) ? 1 : 0;
}

// ---------------- avg pool: mean over L per (b,c) row (all batches) ----------------
__global__ void avg_kernel(const void* __restrict__ xv, const int* __restrict__ flagp,
                           float* __restrict__ avg) {
    const int isf = *flagp;
    const int row = blockIdx.x;                       // b*512 + c, 4096 rows
    float sum = 0.f;
    if (isf) {
        const float4* xr = (const float4*)((const float*)xv + (size_t)row * LEN);
        for (int j = threadIdx.x; j < LEN / 4; j += 256) {
            float4 v = xr[j];
            sum += v.x + v.y + v.z + v.w;
        }
    } else {
        const uint4* xr = (const uint4*)((const u16*)xv + (size_t)row * LEN);
        for (int j = threadIdx.x; j < LEN / 8; j += 256) {
            uint4 v = xr[j];
            unsigned int w[4] = {v.x, v.y, v.z, v.w};
#pragma unroll
            for (int q = 0; q < 4; ++q) {
                sum += __uint_as_float(w[q] << 16);
                sum += __uint_as_float(w[q] & 0xffff0000u);
            }
        }
    }
#pragma unroll
    for (int off = 32; off > 0; off >>= 1) sum += __shfl_down(sum, off, 64);
    __shared__ float red[4];
    if ((threadIdx.x & 63) == 0) red[threadIdx.x >> 6] = sum;
    __syncthreads();
    if (threadIdx.x == 0)
        avg[row] = (red[0] + red[1] + red[2] + red[3]) * (1.0f / LEN);
}

// ------- transpose + L-pad: x[b0+z, i, l] -> xT[z, l+2, i] bf16 (group-local) -------
__global__ void transpose_kernel(const void* __restrict__ xv, const int* __restrict__ flagp,
                                 u16* __restrict__ xT, int b0) {
    const int isf = *flagp;
    __shared__ u16 tile[32][34];
    const int l0 = blockIdx.x * 32, i0 = blockIdx.y * 32, z = blockIdx.z;
    const int tx = threadIdx.x & 31, ty = threadIdx.x >> 5;   // ty 0..7
    const size_t base = ((size_t)((b0 + z) * CIN + i0 + ty) * LEN) + l0 + tx;
#pragma unroll
    for (int j = 0; j < 4; ++j) {
        float v = getv(xv, base + (size_t)(j * 8) * LEN, isf);
        tile[ty + j * 8][tx] = f2bf(v);
    }
    __syncthreads();
    u16* tp = xT + ((size_t)(z * LP) + 2 + l0 + ty) * CIN + i0 + tx;
#pragma unroll
    for (int j = 0; j < 4; ++j)
        tp[(size_t)(j * 8) * CIN] = tile[tx][ty + j * 8];
}

// zero the 4 pad rows (p = 0,1,4098,4099) per group batch — ws is re-poisoned
__global__ void zpad_kernel(u16* __restrict__ xT) {
    int idx = blockIdx.x * 256 + threadIdx.x;   // G*4*512
    int z = idx >> 11;
    int rem = idx & 2047;
    int pr = rem >> 9;                          // 0..3
    int i = rem & 511;
    int p = (pr < 2) ? pr : (4096 + pr);        // 0,1,4098,4099
    xT[((size_t)(z * LP) + p) * CIN + i] = 0;
}

// ---------------- attention branches (fp32 math, all batches) ----------------
__global__ void attn_kernel(const float* __restrict__ avg, const int* __restrict__ flagp,
    const void* kw1, const void* kb1, const void* kw2, const void* kb2,
    const void* sw1, const void* sb1, const void* sw2, const void* sb2,
    const void* iw1, const void* ib1, const void* iw2, const void* ib2,
    const void* ow1, const void* ob1, const void* ow2, const void* ob2,
    float* __restrict__ ka, float* __restrict__ sa,
    float* __restrict__ ia, float* __restrict__ oa) {
    const int isf = *flagp;
    const int br = blockIdx.x >> 3, b = blockIdx.x & 7;
    const void *w1, *b1p, *w2, *b2p; float* op; int od;
    if (br == 0)      { w1 = kw1; b1p = kb1; w2 = kw2; b2p = kb2; op = ka + b * KT;  od = KT;   }
    else if (br == 1) { w1 = sw1; b1p = sb1; w2 = sw2; b2p = sb2; op = sa + b;       od = 1;    }
    else if (br == 2) { w1 = iw1; b1p = ib1; w2 = iw2; b2p = ib2; op = ia + b * CIN; od = CIN;  }
    else              { w1 = ow1; b1p = ob1; w2 = ow2; b2p = ob2; op = oa + b * COUT; od = COUT; }

    __shared__ float av[CIN];
    __shared__ float h[RED_];
    const int t = threadIdx.x;                  // 128 threads
    for (int j = t; j < CIN; j += RED_) av[j] = avg[b * CIN + j];
    __syncthreads();
    float acc = getv(b1p, t, isf);
    const size_t wr = (size_t)t * CIN;
#pragma unroll 4
    for (int c = 0; c < CIN; ++c) acc += av[c] * getv(w1, wr + c, isf);
    h[t] = fmaxf(acc, 0.f);
    __syncthreads();
    for (int o = t; o < od; o += RED_) {
        float a2 = getv(b2p, o, isf);
        const size_t w2r = (size_t)o * RED_;
#pragma unroll 4
        for (int j = 0; j < RED_; ++j) a2 += h[j] * getv(w2, w2r + j, isf);
        op[o] = 1.f / (1.f + expf(-a2));
    }
}

// s[b,o] = sa[b] * ia[b,o] * oa[b,o]   (all batches)
__global__ void scomb_kernel(const float* __restrict__ sa, const float* __restrict__ ia,
                             const float* __restrict__ oa, float* __restrict__ s) {
    int idx = blockIdx.x * 256 + threadIdx.x;   // 4096
    int b = idx >> 9;
    s[idx] = sa[b] * ia[idx] * oa[idx];
}

// wb[z, o, k*512 + i] = bf16( weight[o,i,k] * ka[b0+z,k] )   (group-local)
__global__ void wbgen_kernel(const void* __restrict__ wv, const int* __restrict__ flagp,
                             const float* __restrict__ ka, u16* __restrict__ wb, int b0) {
    const int isf = *flagp;
    int u = blockIdx.x * 256 + threadIdx.x;     // G*512*5*64
    int i8 = (u & 63) << 3;
    int t = u >> 6;                             // z*2560 + o*5 + k
    int k = t % KT;
    int o = (t / KT) & 511;
    int z = t / (KT * 512);
    float kav = ka[(b0 + z) * KT + k];
    const size_t wbase = ((size_t)o * CIN + i8) * KT + k;
    u16x8 r;
#pragma unroll
    for (int j = 0; j < 8; ++j)
        r[j] = f2bf(getv(wv, wbase + (size_t)j * KT, isf) * kav);
    *(u16x8*)(wb + ((size_t)(z * COUT + o)) * KDIM + k * CIN + i8) = r;
}

// -------- main GEMM: out[b,o,l] = s[b,o]*Sum_r wb[z,o,r]*xT[z,l+tap,i] + bias[o] --------
// Register staging (global -> uint4 regs -> ds_write).
__global__ __launch_bounds__(256) void gemm_kernel(
    const u16* __restrict__ wb, const u16* __restrict__ xT,
    const float* __restrict__ s, const void* __restrict__ biasv,
    void* __restrict__ outv, const int* __restrict__ flagp, int b0) {
    const int isf = *flagp;
    __shared__ __align__(16) u16 As[128 * 32];
    __shared__ __align__(16) u16 Bs[128 * 32];
    __shared__ float sm[128], bm[128];

    const int l0 = blockIdx.x * 128;
    const int o0 = blockIdx.y * 128;
    const int z  = blockIdx.z;          // group-local batch
    const int gb = b0 + z;              // global batch
    const int tid = threadIdx.x;

    if (tid < 128) {
        sm[tid] = s[gb * COUT + o0 + tid];
        bm[tid] = getv(biasv, o0 + tid, isf);
    }

    const int lane = tid & 63;
    const int wave = tid >> 6;
    const int wm = (wave >> 1) * 64;
    const int wn = (wave & 1) * 64;
    const int lm = lane & 15;
    const int quad = lane >> 4;

    f32x4 acc[4][4];
#pragma unroll
    for (int i = 0; i < 4; ++i)
#pragma unroll
        for (int j = 0; j < 4; ++j) {
            f32x4 zz = {0.f, 0.f, 0.f, 0.f};
            acc[i][j] = zz;
        }

    const int row = tid >> 2;          // 0..63 (second unit: +64)
    const int c8 = (tid & 3) * 8;      // k-chunk sub-offset (elements)
    const u16* gA = wb + ((size_t)(z * COUT + o0 + row) * KDIM) + c8;
    uint4* lA0 = (uint4*)&As[tid * 8];
    uint4* lA1 = (uint4*)&As[(tid + 256) * 8];
    uint4* lB0 = (uint4*)&Bs[tid * 8];
    uint4* lB1 = (uint4*)&Bs[(tid + 256) * 8];

    for (int r0 = 0; r0 < KDIM; r0 += 32) {
        const int tap = r0 >> 9;       // kernel tap 0..4
        const int i0 = r0 & 511;       // input-channel chunk base
        const u16* gB = xT + ((size_t)(z * LP + l0 + tap + row) * CIN) + i0 + c8;
        uint4 ra0 = *(const uint4*)(gA + r0);
        uint4 ra1 = *(const uint4*)(gA + r0 + (size_t)64 * KDIM);
        uint4 rb0 = *(const uint4*)(gB);
        uint4 rb1 = *(const uint4*)(gB + (size_t)64 * CIN);
        __syncthreads();               // prior iter's LDS reads complete
        *lA0 = ra0;
        *lA1 = ra1;
        *lB0 = rb0;
        *lB1 = rb1;
        __syncthreads();               // publish LDS tile

        bf16x8 af[4], bfr[4];
#pragma unroll
        for (int t = 0; t < 4; ++t) {
            af[t]  = *(const bf16x8*)&As[(wm + t * 16 + lm) * 32 + quad * 8];
            bfr[t] = *(const bf16x8*)&Bs[(wn + t * 16 + lm) * 32 + quad * 8];
        }
#pragma unroll
        for (int mt = 0; mt < 4; ++mt)
#pragma unroll
            for (int nt = 0; nt < 4; ++nt)
                acc[mt][nt] = __builtin_amdgcn_mfma_f32_16x16x32_bf16(
                    af[mt], bfr[nt], acc[mt][nt], 0, 0, 0);
    }

    // epilogue: out = s*acc + bias, C/D layout col=lane&15, row=quad*4+reg
#pragma unroll
    for (int mt = 0; mt < 4; ++mt) {
        const int mb = wm + mt * 16 + quad * 4;
        float sv[4], bv[4];
#pragma unroll
        for (int r = 0; r < 4; ++r) { sv[r] = sm[mb + r]; bv[r] = bm[mb + r]; }
#pragma unroll
        for (int nt = 0; nt < 4; ++nt) {
            const int col = l0 + wn + nt * 16 + lm;
            const size_t obase = ((size_t)(gb * COUT + o0 + mb)) * LEN + col;
#pragma unroll
            for (int r = 0; r < 4; ++r) {
                float val = sv[r] * acc[mt][nt][r] + bv[r];
                if (isf) ((float*)outv)[obase + (size_t)r * LEN] = val;
                else     ((u16*)outv)[obase + (size_t)r * LEN] = f2bf(val);
            }
        }
    }
}

extern "C" void kernel_launch(void* const* d_in, const int* in_sizes, int n_in,
                              void* d_out, int out_size, void* d_ws, size_t ws_size,
                              hipStream_t stream) {
    const void* x      = d_in[0];
    const void* weight = d_in[1];
    const void* bias   = d_in[2];

    // ---- pick largest batch-group size G that fits the workspace ----
    const size_t small_bytes = 96 * 1024;   // fp32 side buffers + flag + slop
    int G = 8;
    while (G > 1) {
        size_t need = (size_t)G * (XT_B + WB_B) * sizeof(u16) + small_bytes;
        if (need <= ws_size) break;
        G >>= 1;
    }

    char* ws = (char*)d_ws;
    size_t off = 0;
    auto alloc = [&](size_t bytes) {
        void* p = ws + off;
        off += (bytes + 255) & ~(size_t)255;
        return p;
    };
    u16*   xT   = (u16*)alloc((size_t)G * XT_B * sizeof(u16));
    u16*   wbuf = (u16*)alloc((size_t)G * WB_B * sizeof(u16));
    int*   flag = (int*)alloc(sizeof(int));
    float* avg  = (float*)alloc((size_t)B_ * CIN * sizeof(float));
    float* ka   = (float*)alloc((size_t)B_ * KT * sizeof(float));
    float* sa   = (float*)alloc((size_t)B_ * sizeof(float));
    float* ia   = (float*)alloc((size_t)B_ * CIN * sizeof(float));
    float* oa   = (float*)alloc((size_t)B_ * COUT * sizeof(float));
    float* sfac = (float*)alloc((size_t)B_ * COUT * sizeof(float));

    // dtype detect + batch-global prep
    detect_kernel<<<1, 256, 0, stream>>>(x, flag);
    avg_kernel<<<B_ * CIN, 256, 0, stream>>>(x, flag, avg);
    attn_kernel<<<32, RED_, 0, stream>>>(avg, flag,
        d_in[3],  d_in[4],  d_in[5],  d_in[6],
        d_in[7],  d_in[8],  d_in[9],  d_in[10],
        d_in[11], d_in[12], d_in[13], d_in[14],
        d_in[15], d_in[16], d_in[17], d_in[18],
        ka, sa, ia, oa);
    scomb_kernel<<<(B_ * COUT) / 256, 256, 0, stream>>>(sa, ia, oa, sfac);

    // per-group: transpose + pad + dyn-weight + GEMM
    for (int b0 = 0; b0 < B_; b0 += G) {
        transpose_kernel<<<dim3(LEN / 32, CIN / 32, G), 256, 0, stream>>>(x, flag, xT, b0);
        zpad_kernel<<<(G * 4 * CIN) / 256, 256, 0, stream>>>(xT);
        wbgen_kernel<<<(G * COUT * KT * 64) / 256, 256, 0, stream>>>(weight, flag, ka, wbuf, b0);
        gemm_kernel<<<dim3(LEN / 128, COUT / 128, G), 256, 0, stream>>>(
            wbuf, xT, sfac, bias, d_out, flag, b0);
    }
}

// Round 5
// 301.081 us; speedup vs baseline: 1.2925x; 1.2925x over previous
//
#include <hip/hip_runtime.h>

typedef unsigned short u16;
typedef __bf16 bf16x8 __attribute__((ext_vector_type(8)));
typedef float f32x4 __attribute__((ext_vector_type(4)));
typedef u16 u16x8 __attribute__((ext_vector_type(8)));

#define B_    8
#define CIN   512
#define COUT  512
#define KT    5
#define LEN   4096
#define RED_  128
#define KDIM  (KT * CIN)   /* 2560 */
#define BSR   40           /* Bs row stride (elems): 80 B = 20 banks, 16B-aligned */

__device__ __forceinline__ u16 f2bf(float f) {
    unsigned int u = __float_as_uint(f);
    u += 0x7fffu + ((u >> 16) & 1u);   // RNE
    return (u16)(u >> 16);
}

typedef __attribute__((address_space(1))) void gvoid_t;
typedef __attribute__((address_space(3))) void lvoid_t;
__device__ __forceinline__ void glds16(const u16* g, u16* l) {
    __builtin_amdgcn_global_load_lds((gvoid_t*)g, (lvoid_t*)l, 16, 0, 0);
}

// ---------------- avg pool: mean over L per (b,c) row ----------------
__global__ void avg_kernel(const float* __restrict__ x, float* __restrict__ avg) {
    const int row = blockIdx.x;                       // b*512 + c, 4096 rows
    const float4* xr = (const float4*)(x + (size_t)row * LEN);
    float sum = 0.f;
    for (int j = threadIdx.x; j < LEN / 4; j += 256) {
        float4 v = xr[j];
        sum += v.x + v.y + v.z + v.w;
    }
#pragma unroll
    for (int off = 32; off > 0; off >>= 1) sum += __shfl_down(sum, off, 64);
    __shared__ float red[4];
    if ((threadIdx.x & 63) == 0) red[threadIdx.x >> 6] = sum;
    __syncthreads();
    if (threadIdx.x == 0)
        avg[row] = (red[0] + red[1] + red[2] + red[3]) * (1.0f / LEN);
}

// ---------------- attention branches (fp32, float4-vectorized) ----------------
__global__ void attn_kernel(const float* __restrict__ avg,
    const float* kw1, const float* kb1, const float* kw2, const float* kb2,
    const float* sw1, const float* sb1, const float* sw2, const float* sb2,
    const float* iw1, const float* ib1, const float* iw2, const float* ib2,
    const float* ow1, const float* ob1, const float* ow2, const float* ob2,
    float* __restrict__ ka, float* __restrict__ sa,
    float* __restrict__ ia, float* __restrict__ oa) {
    const int br = blockIdx.x >> 3, b = blockIdx.x & 7;
    const float *w1, *b1p, *w2, *b2p; float* op; int od;
    if (br == 0)      { w1 = kw1; b1p = kb1; w2 = kw2; b2p = kb2; op = ka + b * KT;  od = KT;   }
    else if (br == 1) { w1 = sw1; b1p = sb1; w2 = sw2; b2p = sb2; op = sa + b;       od = 1;    }
    else if (br == 2) { w1 = iw1; b1p = ib1; w2 = iw2; b2p = ib2; op = ia + b * CIN; od = CIN;  }
    else              { w1 = ow1; b1p = ob1; w2 = ow2; b2p = ob2; op = oa + b * COUT; od = COUT; }

    __shared__ float av[CIN];
    __shared__ float h[RED_];
    const int t = threadIdx.x;                  // 128 threads
    for (int j = t; j < CIN; j += RED_) av[j] = avg[b * CIN + j];
    __syncthreads();
    float acc = b1p[t];
    const float4* wr = (const float4*)(w1 + (size_t)t * CIN);
#pragma unroll 4
    for (int c = 0; c < CIN / 4; ++c) {
        float4 w = wr[c];
        acc += av[4 * c] * w.x + av[4 * c + 1] * w.y + av[4 * c + 2] * w.z + av[4 * c + 3] * w.w;
    }
    h[t] = fmaxf(acc, 0.f);
    __syncthreads();
    for (int o = t; o < od; o += RED_) {
        float a2 = b2p[o];
        const float4* w2r = (const float4*)(w2 + (size_t)o * RED_);
#pragma unroll 4
        for (int j = 0; j < RED_ / 4; ++j) {
            float4 w = w2r[j];
            a2 += h[4 * j] * w.x + h[4 * j + 1] * w.y + h[4 * j + 2] * w.z + h[4 * j + 3] * w.w;
        }
        op[o] = 1.f / (1.f + expf(-a2));
    }
}

// s[b,o] = sa[b] * ia[b,o] * oa[b,o]
__global__ void scomb_kernel(const float* __restrict__ sa, const float* __restrict__ ia,
                             const float* __restrict__ oa, float* __restrict__ s) {
    int idx = blockIdx.x * 256 + threadIdx.x;   // 4096
    int b = idx >> 9;
    s[idx] = sa[b] * ia[idx] * oa[idx];
}

// wb[b, o, k*512 + i] = bf16( weight[o,i,k] * ka[b,k] )   (all 8 batches, 21 MB)
__global__ void wbgen_kernel(const float* __restrict__ w, const float* __restrict__ ka,
                             u16* __restrict__ wb) {
    int u = blockIdx.x * 256 + threadIdx.x;     // 8*512*5*64 = 1,310,720
    int i8 = (u & 63) << 3;
    int t = u >> 6;                             // b*2560 + o*5 + k
    int k = t % KT;
    int o = (t / KT) & 511;
    int b = t / (KT * 512);
    float kav = ka[b * KT + k];
    const float* wp = w + ((size_t)o * CIN + i8) * KT + k;
    u16x8 r;
#pragma unroll
    for (int j = 0; j < 8; ++j) r[j] = f2bf(wp[(size_t)j * KT] * kav);
    *(u16x8*)(wb + ((size_t)(b * COUT + o)) * KDIM + k * CIN + i8) = r;
}

// ---- main GEMM: out[b,o,l] = s[b,o] * Sum_{tap,i} wb[b,o,tap*512+i] * x[b,i,l+tap-2] + bias[o]
// A staged via global_load_lds (5 taps per i-chunk); B transposed fp32->bf16 in-kernel.
__global__ __launch_bounds__(256) void gemm_kernel(
    const u16* __restrict__ wb, const float* __restrict__ x,
    const float* __restrict__ s, const float* __restrict__ bias,
    float* __restrict__ out) {
    __shared__ __align__(16) u16 As[5 * 128 * 32];   // [tap][o-row][32]  40960 B
    __shared__ __align__(16) u16 Bs[132 * BSR];      // [lw][i], stride 40 elems  10560 B
    __shared__ float sm[128], bm[128];

    const int l0 = blockIdx.x * 128;
    const int o0 = blockIdx.y * 128;
    const int b  = blockIdx.z;
    const int tid = threadIdx.x;

    if (tid < 128) {
        sm[tid] = s[b * COUT + o0 + tid];
        bm[tid] = bias[o0 + tid];
    }

    const int lane = tid & 63;
    const int wave = tid >> 6;
    const int wm = (wave >> 1) * 64;
    const int wn = (wave & 1) * 64;
    const int lm = lane & 15;
    const int quad = lane >> 4;

    f32x4 acc[4][4];
#pragma unroll
    for (int i = 0; i < 4; ++i)
#pragma unroll
        for (int j = 0; j < 4; ++j) {
            f32x4 zz = {0.f, 0.f, 0.f, 0.f};
            acc[i][j] = zz;
        }

    const float* xb = x + (size_t)b * CIN * LEN;
    // A staging map: 4 lanes per o-row, 8 elems each
    const u16* gA = wb + ((size_t)(b * COUT + o0 + (tid >> 2))) * KDIM + (tid & 3) * 8;
    // B staging map: row-groups of 64 l-rows, 4 i-groups of 8
    const int lwA = tid & 63;
    const int igA = (tid >> 6) * 8;

#pragma unroll 1
    for (int ic = 0; ic < 16; ++ic) {
        const int i0 = ic * 32;
        // ---- A: 10 DMA stages (5 taps x 2 row-halves) ----
#pragma unroll
        for (int t = 0; t < KT; ++t) {
            glds16(gA + t * 512 + i0, &As[t * 4096 + tid * 8]);
            glds16(gA + (size_t)64 * KDIM + t * 512 + i0, &As[t * 4096 + 2048 + tid * 8]);
        }
        // ---- B: 132 x 32 fp32 -> bf16, transposed into Bs ----
#pragma unroll
        for (int rg = 0; rg < 2; ++rg) {
            const int lw = lwA + rg * 64;
            const int lg = l0 - 2 + lw;
            if (lg >= 0 && lg < LEN) {
                const float* xp = xb + (size_t)(i0 + igA) * LEN + lg;
                unsigned d0, d1, d2, d3;
                {
                    unsigned a = __float_as_uint(xp[0]);
                    unsigned c = __float_as_uint(xp[(size_t)LEN]);
                    d0 = __builtin_amdgcn_perm(c, a, 0x07060302);
                    a = __float_as_uint(xp[(size_t)2 * LEN]);
                    c = __float_as_uint(xp[(size_t)3 * LEN]);
                    d1 = __builtin_amdgcn_perm(c, a, 0x07060302);
                    a = __float_as_uint(xp[(size_t)4 * LEN]);
                    c = __float_as_uint(xp[(size_t)5 * LEN]);
                    d2 = __builtin_amdgcn_perm(c, a, 0x07060302);
                    a = __float_as_uint(xp[(size_t)6 * LEN]);
                    c = __float_as_uint(xp[(size_t)7 * LEN]);
                    d3 = __builtin_amdgcn_perm(c, a, 0x07060302);
                }
                *(uint4*)&Bs[lw * BSR + igA] = make_uint4(d0, d1, d2, d3);
            } else {
                *(uint4*)&Bs[lw * BSR + igA] = make_uint4(0, 0, 0, 0);
            }
        }
        if (tid < 16) {                       // tail rows 128..131
            const int lw = 128 + (tid >> 2);
            const int ig = (tid & 3) * 8;
            const int lg = l0 - 2 + lw;
            if (lg >= 0 && lg < LEN) {
                const float* xp = xb + (size_t)(i0 + ig) * LEN + lg;
                unsigned d[4];
#pragma unroll
                for (int jj = 0; jj < 4; ++jj) {
                    unsigned a = __float_as_uint(xp[(size_t)(2 * jj) * LEN]);
                    unsigned c = __float_as_uint(xp[(size_t)(2 * jj + 1) * LEN]);
                    d[jj] = __builtin_amdgcn_perm(c, a, 0x07060302);
                }
                *(uint4*)&Bs[lw * BSR + ig] = make_uint4(d[0], d[1], d[2], d[3]);
            } else {
                *(uint4*)&Bs[lw * BSR + ig] = make_uint4(0, 0, 0, 0);
            }
        }
        __syncthreads();

        // ---- compute: 5 taps x 16 MFMA ----
#pragma unroll
        for (int t = 0; t < KT; ++t) {
            bf16x8 af[4], bfr[4];
#pragma unroll
            for (int f = 0; f < 4; ++f) {
                af[f]  = *(const bf16x8*)&As[t * 4096 + (wm + f * 16 + lm) * 32 + quad * 8];
                bfr[f] = *(const bf16x8*)&Bs[(wn + f * 16 + lm + t) * BSR + quad * 8];
            }
#pragma unroll
            for (int mt = 0; mt < 4; ++mt)
#pragma unroll
                for (int nt = 0; nt < 4; ++nt)
                    acc[mt][nt] = __builtin_amdgcn_mfma_f32_16x16x32_bf16(
                        af[mt], bfr[nt], acc[mt][nt], 0, 0, 0);
        }
        __syncthreads();
    }

    // epilogue: out = s*acc + bias, C/D layout col=lane&15, row=quad*4+reg
#pragma unroll
    for (int mt = 0; mt < 4; ++mt) {
        const int mb = wm + mt * 16 + quad * 4;
        float sv[4], bv[4];
#pragma unroll
        for (int r = 0; r < 4; ++r) { sv[r] = sm[mb + r]; bv[r] = bm[mb + r]; }
#pragma unroll
        for (int nt = 0; nt < 4; ++nt) {
            const int col = l0 + wn + nt * 16 + lm;
            float* op = out + ((size_t)(b * COUT + o0 + mb)) * LEN + col;
#pragma unroll
            for (int r = 0; r < 4; ++r)
                op[(size_t)r * LEN] = sv[r] * acc[mt][nt][r] + bv[r];
        }
    }
}

extern "C" void kernel_launch(void* const* d_in, const int* in_sizes, int n_in,
                              void* d_out, int out_size, void* d_ws, size_t ws_size,
                              hipStream_t stream) {
    const float* x      = (const float*)d_in[0];
    const float* weight = (const float*)d_in[1];
    const float* bias   = (const float*)d_in[2];
    float* out = (float*)d_out;

    char* ws = (char*)d_ws;
    size_t off = 0;
    auto alloc = [&](size_t bytes) {
        void* p = ws + off;
        off += (bytes + 255) & ~(size_t)255;
        return p;
    };
    u16*   wbuf = (u16*)alloc((size_t)B_ * COUT * KDIM * sizeof(u16));  // 21.0 MB
    float* avg  = (float*)alloc((size_t)B_ * CIN * sizeof(float));
    float* ka   = (float*)alloc((size_t)B_ * KT * sizeof(float));
    float* sa   = (float*)alloc((size_t)B_ * sizeof(float));
    float* ia   = (float*)alloc((size_t)B_ * CIN * sizeof(float));
    float* oa   = (float*)alloc((size_t)B_ * COUT * sizeof(float));
    float* sfac = (float*)alloc((size_t)B_ * COUT * sizeof(float));

    avg_kernel<<<B_ * CIN, 256, 0, stream>>>(x, avg);
    attn_kernel<<<32, RED_, 0, stream>>>(avg,
        (const float*)d_in[3],  (const float*)d_in[4],  (const float*)d_in[5],  (const float*)d_in[6],
        (const float*)d_in[7],  (const float*)d_in[8],  (const float*)d_in[9],  (const float*)d_in[10],
        (const float*)d_in[11], (const float*)d_in[12], (const float*)d_in[13], (const float*)d_in[14],
        (const float*)d_in[15], (const float*)d_in[16], (const float*)d_in[17], (const float*)d_in[18],
        ka, sa, ia, oa);
    scomb_kernel<<<(B_ * COUT) / 256, 256, 0, stream>>>(sa, ia, oa, sfac);
    wbgen_kernel<<<(B_ * COUT * KT * 64) / 256, 256, 0, stream>>>(weight, ka, wbuf);
    gemm_kernel<<<dim3(LEN / 128, COUT / 128, B_), 256, 0, stream>>>(
        wbuf, x, sfac, bias, out);
}